// Round 1
// baseline (183.257 us; speedup 1.0000x reference)
//
#include <hip/hip_runtime.h>
#include <math.h>

#ifndef M_PI
#define M_PI 3.14159265358979323846
#endif

#define NS 7      // NUM_SPHERICAL
#define NK 6      // NUM_RADIAL
#define GT 64     // triplets per block
#define BT 256    // threads per block

// ---------------- setup: bessel zeros, norms, sph-harm prefactors -----------
// tab layout (floats): [0..41] zeros (l*6+j), [42..83] norm, [84..132] coef(49)

__device__ double d_sph_jl(double x, int l) {
  double s = sin(x), c = cos(x);
  double j0 = s / x;
  if (l == 0) return j0;
  double j1 = s / (x * x) - c / x;
  for (int ll = 2; ll <= l; ++ll) {
    double t = (2.0 * ll - 1.0) / x * j1 - j0;
    j0 = j1; j1 = t;
  }
  return j1;
}

__global__ void setup_kernel(float* tab) {
  int id = threadIdx.x;
  if (id < NS * NK) {
    int l = id / NK, j = id % NK;
    // McMahon expansion seed for the (j+1)-th zero of J_{l+1/2} == j_l
    double nu = l + 0.5;
    double mu = 4.0 * nu * nu;
    double b  = ((double)(j + 1) + 0.5 * nu - 0.25) * M_PI;
    double b8 = 8.0 * b;
    double x = b - (mu - 1.0) / b8
                 - 4.0 * (mu - 1.0) * (7.0 * mu - 31.0) / (3.0 * b8 * b8 * b8)
                 - 32.0 * (mu - 1.0) * (83.0 * mu * mu - 982.0 * mu + 3779.0) /
                   (15.0 * b8 * b8 * b8 * b8 * b8);
    // Newton polish: j_l'(x) = j_{l-1}(x) - (l+1)/x * j_l(x), j_{-1}=cos(x)/x
    for (int it = 0; it < 12; ++it) {
      double jl  = d_sph_jl(x, l);
      double jm1 = (l == 0) ? cos(x) / x : d_sph_jl(x, l - 1);
      double dj  = jm1 - (l + 1.0) / x * jl;
      x -= jl / dj;
    }
    tab[id] = (float)x;
    double jn = d_sph_jl(x, l + 1);
    tab[NS * NK + id] = (float)(sqrt(2.0) / fabs(jn));
  }
  if (id < NS * NS) {
    double v;
    if (id == 0) {
      v = 0.5 / sqrt(M_PI);
    } else {
      int l = 1;
      while ((l + 1) * (l + 1) <= id) ++l;     // l = isqrt(id)
      int m  = id - l * l - l;                  // -l..l
      int am = m < 0 ? -m : m;
      double fr = 1.0;                          // (l+am)! / (l-am)!
      for (int i2 = l - am + 1; i2 <= l + am; ++i2) fr *= (double)i2;
      double pref = sqrt((2.0 * l + 1.0) / (4.0 * M_PI * fr));
      v = (m != 0) ? sqrt(2.0) * pref : pref;
    }
    tab[2 * NS * NK + id] = (float)v;
  }
}

// ---------------- main kernel ----------------------------------------------
__global__ __launch_bounds__(BT) void torsion_kernel(
    const float* __restrict__ dist, const float* __restrict__ angle,
    const float* __restrict__ phi, const int* __restrict__ idx_kj,
    const float* __restrict__ tab, float* __restrict__ out, int T) {
  __shared__ float s_cbf[GT][NS * NS];           // 64 x 49
  __shared__ __align__(16) float s_rbf[GT][NS * NK];  // 64 x 42
  __shared__ float s_d[GT];

  const int tid = threadIdx.x;
  const int t0  = blockIdx.x * GT;
  const int nt  = min(GT, T - t0);

  // gather dist for the 64 triplets
  if (tid < GT) {
    int t = t0 + tid;
    float dd = 1.0f;                              // safe dummy for tail
    if (t < T) dd = dist[idx_kj[t]] / 5.0f;       // dist / CUTOFF
    s_d[tid] = dd;
  }
  __syncthreads();

  // ---- cbf: lanes 0..63, one triplet each, all-register unrolled ----
  if (tid < GT && tid < nt) {
    int t = t0 + tid;
    float a = angle[t], ph = phi[t];
    float z = cosf(a), s = sinf(a);
    float P[NS][NS];
    P[0][0] = 1.0f;
#pragma unroll
    for (int m = 1; m < NS; ++m) P[m][m] = (float)(1 - 2 * m) * s * P[m - 1][m - 1];
#pragma unroll
    for (int m = 0; m < NS - 1; ++m) P[m + 1][m] = (float)(2 * m + 1) * z * P[m][m];
#pragma unroll
    for (int m = 0; m < NS; ++m)
#pragma unroll
      for (int l = m + 2; l < NS; ++l)
        P[l][m] = ((float)(2 * l - 1) * z * P[l - 1][m] -
                   (float)(l + m - 1) * P[l - 2][m]) / (float)(l - m);

    float sp, cp;
    sincosf(ph, &sp, &cp);
    float cmv[NS], smv[NS];
    cmv[0] = 1.0f; smv[0] = 0.0f;
    cmv[1] = cp;   smv[1] = sp;
#pragma unroll
    for (int m = 2; m < NS; ++m) {
      cmv[m] = 2.0f * cp * cmv[m - 1] - cmv[m - 2];
      smv[m] = 2.0f * cp * smv[m - 1] - smv[m - 2];
    }
    const float* coef = tab + 2 * NS * NK;
    s_cbf[tid][0] = coef[0];
    int c = 1;
#pragma unroll
    for (int l = 1; l < NS; ++l) {
#pragma unroll
      for (int m = -l; m <= l; ++m) {
        int am = m < 0 ? -m : m;
        float trig = (m < 0) ? smv[am] : ((m > 0) ? cmv[am] : 1.0f);
        s_cbf[tid][c] = coef[c] * trig * P[l][am];
        ++c;
      }
    }
  }

  // ---- rbf: all 256 threads cover 64*42 values ----
  for (int i2 = tid; i2 < GT * NS * NK; i2 += BT) {
    int t  = i2 / (NS * NK);
    int cc = i2 - (NS * NK) * t;                 // l*6 + j
    int l  = cc / NK;
    float x = s_d[t] * tab[cc];
    float sx, cx;
    sincosf(x, &sx, &cx);
    float invx = 1.0f / x;
    float jm = sx * invx;
    float jc = jm;
    if (l > 0) {
      jc = (sx * invx - cx) * invx;
#pragma unroll 5
      for (int ll = 2; ll <= l; ++ll) {
        float tt = (float)(2 * ll - 1) * invx * jc - jm;
        jm = jc; jc = tt;
      }
    }
    s_rbf[t][cc] = tab[NS * NK + cc] * jc;
  }
  __syncthreads();

  // ---- phase 2: coalesced float2 stores of 64 x 294 outputs ----
  // out[t, i*42 + jj*6 + r] = cbf[t, i*7+jj] * rbf[t, jj*6+r]
  const float2* r2 = (const float2*)&s_rbf[0][0];   // row stride 21 float2
  float2* o2 = (float2*)out + (size_t)t0 * 147;
  int tot = nt * 147;
  for (int i = tid; i < tot; i += BT) {
    int t    = i / 147;
    int c2   = i - 147 * t;
    int ii   = c2 / 21;           // spherical index i
    int rem2 = c2 - 21 * ii;      // float2 index in rbf row; jj = rem2/3
    int jj   = rem2 / 3;
    float  cv = s_cbf[t][ii * NS + jj];
    float2 rv = r2[t * 21 + rem2];
    float2 ov; ov.x = cv * rv.x; ov.y = cv * rv.y;
    o2[i] = ov;
  }
}

// ---------------- launch ----------------------------------------------------
extern "C" void kernel_launch(void* const* d_in, const int* in_sizes, int n_in,
                              void* d_out, int out_size, void* d_ws, size_t ws_size,
                              hipStream_t stream) {
  const float* dist  = (const float*)d_in[0];
  const float* angle = (const float*)d_in[1];
  const float* phi   = (const float*)d_in[2];
  const int*   idx   = (const int*)d_in[3];
  float* out = (float*)d_out;
  float* tab = (float*)d_ws;          // 133 floats
  int T = in_sizes[1];

  hipLaunchKernelGGL(setup_kernel, dim3(1), dim3(64), 0, stream, tab);
  int nb = (T + GT - 1) / GT;
  hipLaunchKernelGGL(torsion_kernel, dim3(nb), dim3(BT), 0, stream,
                     dist, angle, phi, idx, tab, out, T);
}

// Round 3
// 136.499 us; speedup vs baseline: 1.3426x; 1.3426x over previous
//
#include <hip/hip_runtime.h>
#include <math.h>

#ifndef M_PI
#define M_PI 3.14159265358979323846
#endif

#define NS 7      // NUM_SPHERICAL
#define NK 6      // NUM_RADIAL
#define GT 64     // triplets per block
#define BT 256    // threads per block
#define NC (NS*NS)   // 49
#define NR (NS*NK)   // 42
#define NF2 147      // output float2 per triplet (294/2)

typedef float f32x2 __attribute__((ext_vector_type(2)));

// tab layout (floats): [0..41] zeros (l*6+j), [42..83] norm, [84..132] coef(49)

__device__ double d_sph_jl(double x, int l) {
  double s = sin(x), c = cos(x);
  double j0 = s / x;
  if (l == 0) return j0;
  double j1 = s / (x * x) - c / x;
  for (int ll = 2; ll <= l; ++ll) {
    double t = (2.0 * ll - 1.0) / x * j1 - j0;
    j0 = j1; j1 = t;
  }
  return j1;
}

__global__ void setup_kernel(float* tab) {
  int id = threadIdx.x;
  if (id < NS * NK) {
    int l = id / NK, j = id % NK;
    double nu = l + 0.5;
    double mu = 4.0 * nu * nu;
    double b  = ((double)(j + 1) + 0.5 * nu - 0.25) * M_PI;
    double b8 = 8.0 * b;
    double x = b - (mu - 1.0) / b8
                 - 4.0 * (mu - 1.0) * (7.0 * mu - 31.0) / (3.0 * b8 * b8 * b8)
                 - 32.0 * (mu - 1.0) * (83.0 * mu * mu - 982.0 * mu + 3779.0) /
                   (15.0 * b8 * b8 * b8 * b8 * b8);
    for (int it = 0; it < 6; ++it) {
      double jl  = d_sph_jl(x, l);
      double jm1 = (l == 0) ? cos(x) / x : d_sph_jl(x, l - 1);
      double dj  = jm1 - (l + 1.0) / x * jl;
      x -= jl / dj;
    }
    tab[id] = (float)x;
    double jn = d_sph_jl(x, l + 1);
    tab[NS * NK + id] = (float)(sqrt(2.0) / fabs(jn));
  }
  if (id < NS * NS) {
    double v;
    if (id == 0) {
      v = 0.5 / sqrt(M_PI);
    } else {
      int l = 1;
      while ((l + 1) * (l + 1) <= id) ++l;
      int m  = id - l * l - l;
      int am = m < 0 ? -m : m;
      double fr = 1.0;
      for (int i2 = l - am + 1; i2 <= l + am; ++i2) fr *= (double)i2;
      double pref = sqrt((2.0 * l + 1.0) / (4.0 * M_PI * fr));
      v = (m != 0) ? sqrt(2.0) * pref : pref;
    }
    tab[2 * NS * NK + id] = (float)v;
  }
}

// ---------------- main kernel ----------------------------------------------
__global__ __launch_bounds__(BT, 4) void torsion_kernel(
    const float* __restrict__ dist, const float* __restrict__ angle,
    const float* __restrict__ phi, const int* __restrict__ idx_kj,
    const float* __restrict__ tab, float* __restrict__ out, int T) {
  __shared__ float s_cbf[GT][NC];                       // 64 x 49
  __shared__ __align__(16) float s_rbf[GT][NR];         // 64 x 42
  __shared__ float s_d[GT];
  __shared__ float s_tab[133];
  __shared__ unsigned short s_map[NF2 + 1];

  const int tid = threadIdx.x;
  const int t0  = blockIdx.x * GT;
  const int nt  = min(GT, T - t0);

  // ---- phase 0: gathers + LDS tables ----
  if (tid < GT) {
    int t = t0 + tid;
    float dd = 1.0f;
    if (t < T) dd = dist[idx_kj[t]] * 0.2f;   // /CUTOFF
    s_d[tid] = dd;
  }
  if (tid < 133) s_tab[tid] = tab[tid];
  if (tid < NF2) {
    int ii = tid / 21, rem2 = tid - 21 * ii, jj = rem2 / 3;
    s_map[tid] = (unsigned short)((ii * NS + jj) | (rem2 << 8));
  }
  __syncthreads();

  // ---- cbf: lanes 0..63, per-m streaming Legendre (low VGPR) ----
  if (tid < GT) {
    int t = t0 + tid;
    if (t < T) {
      float a = angle[t], ph = phi[t];
      float z = cosf(a), s = sinf(a);
      float sp, cp;
      sincosf(ph, &sp, &cp);
      float cmv[NS], smv[NS];
      cmv[0] = 1.0f; smv[0] = 0.0f;
      cmv[1] = cp;   smv[1] = sp;
#pragma unroll
      for (int m = 2; m < NS; ++m) {
        cmv[m] = 2.0f * cp * cmv[m - 1] - cmv[m - 2];
        smv[m] = 2.0f * cp * smv[m - 1] - smv[m - 2];
      }
      const float* coef = s_tab + 2 * NR;
      float* crow = s_cbf[tid];
      float pmm = 1.0f;
#pragma unroll
      for (int m = 0; m < NS; ++m) {
        float pl1 = pmm, pl2 = 0.0f;
#pragma unroll
        for (int l = m; l < NS; ++l) {
          float plm;
          if (l == m)          plm = pmm;
          else if (l == m + 1) plm = (float)(2 * m + 1) * z * pmm;
          else                 plm = ((float)(2 * l - 1) * z * pl1 -
                                      (float)(l + m - 1) * pl2) *
                                     (float)(1.0 / (double)(l - m));
          int cpn = l * l + l + m;
          if (m == 0) {
            crow[cpn] = coef[cpn] * plm;
          } else {
            crow[cpn] = coef[cpn] * cmv[m] * plm;
            int cmn = l * l + l - m;
            crow[cmn] = coef[cmn] * smv[m] * plm;
          }
          pl2 = pl1; pl1 = plm;
        }
        pmm = (float)(-1 - 2 * m) * s * pmm;   // P[m+1][m+1]
      }
    }
  }

  // ---- rbf: all 256 threads, incremental index walk ----
  {
    int i2 = tid;
    int t  = tid / NR;              // tid<256 -> t in 0..6
    int cc = tid - NR * t;
    float* rlin = &s_rbf[0][0];
    while (i2 < GT * NR) {
      int l = (cc * 43) >> 8;       // cc/6 for cc<42
      float x = s_d[t] * s_tab[cc];
      float sx, cx;
      sincosf(x, &sx, &cx);
      float invx = 1.0f / x;
      float jm = sx * invx;
      float jc;
      if (l == 0) jc = jm;
      else {
        jc = (sx * invx - cx) * invx;
#pragma unroll
        for (int ll = 2; ll <= 6; ++ll) {
          if (ll <= l) {
            float tt = (float)(2 * ll - 1) * invx * jc - jm;
            jm = jc; jc = tt;
          }
        }
      }
      rlin[i2] = s_tab[NR + cc] * jc;
      i2 += BT;
      cc += 4; t += 6;              // 256 = 6*42 + 4
      if (cc >= NR) { cc -= NR; ++t; }
    }
  }
  __syncthreads();

  // ---- store: coalesced float2, zero-division index walk ----
  const f32x2* r2 = (const f32x2*)&s_rbf[0][0];   // row stride 21 f32x2
  f32x2* o2 = (f32x2*)out + (size_t)t0 * NF2;

  if (nt == GT) {
    int i = tid;
    int t = 0, c2 = tid;
    if (c2 >= NF2) { c2 -= NF2; t = 1; }
#pragma unroll 4
    for (int k = 0; k < 36; ++k) {               // 36*256 + 192 = 9408
      unsigned int mp = s_map[c2];
      float cv = s_cbf[t][mp & 0xff];
      f32x2 rv = r2[t * 21 + (mp >> 8)];
      f32x2 ov = cv * rv;
      __builtin_nontemporal_store(ov, o2 + i);
      i += BT;
      c2 += 109; ++t;                            // 256 = 147 + 109
      if (c2 >= NF2) { c2 -= NF2; ++t; }
    }
    if (tid < 192) {                             // tail 9216..9407
      unsigned int mp = s_map[c2];
      float cv = s_cbf[t][mp & 0xff];
      f32x2 rv = r2[t * 21 + (mp >> 8)];
      f32x2 ov = cv * rv;
      __builtin_nontemporal_store(ov, o2 + i);
    }
  } else {
    int tot = nt * NF2;
    for (int i = tid; i < tot; i += BT) {
      int t  = i / NF2;
      int c2 = i - NF2 * t;
      unsigned int mp = s_map[c2];
      float cv = s_cbf[t][mp & 0xff];
      f32x2 rv = r2[t * 21 + (mp >> 8)];
      f32x2 ov = cv * rv;
      __builtin_nontemporal_store(ov, o2 + i);
    }
  }
}

// ---------------- launch ----------------------------------------------------
extern "C" void kernel_launch(void* const* d_in, const int* in_sizes, int n_in,
                              void* d_out, int out_size, void* d_ws, size_t ws_size,
                              hipStream_t stream) {
  const float* dist  = (const float*)d_in[0];
  const float* angle = (const float*)d_in[1];
  const float* phi   = (const float*)d_in[2];
  const int*   idx   = (const int*)d_in[3];
  float* out = (float*)d_out;
  float* tab = (float*)d_ws;          // 133 floats
  int T = in_sizes[1];

  hipLaunchKernelGGL(setup_kernel, dim3(1), dim3(64), 0, stream, tab);
  int nb = (T + GT - 1) / GT;
  hipLaunchKernelGGL(torsion_kernel, dim3(nb), dim3(BT), 0, stream,
                     dist, angle, phi, idx, tab, out, T);
}

// Round 4
// 127.964 us; speedup vs baseline: 1.4321x; 1.0667x over previous
//
#include <hip/hip_runtime.h>
#include <math.h>

#ifndef M_PI
#define M_PI 3.14159265358979323846
#endif

#define NS 7      // NUM_SPHERICAL
#define NK 6      // NUM_RADIAL
#define GT 64     // triplets per block
#define BT 256    // threads per block
#define NC (NS*NS)   // 49
#define NR (NS*NK)   // 42
#define NF2 147      // float2 per triplet row (294/2)

typedef float f32x2 __attribute__((ext_vector_type(2)));
typedef float f32x4 __attribute__((ext_vector_type(4)));

// tab layout (floats): [0..41] zeros (l*6+j), [42..83] norm, [84..132] coef(49)

// fused recurrence: returns j_l(x) and j_{l-1}(x)  (j_{-1} = cos x / x)
__device__ void jl_pair(double x, int l, double& jl, double& jm1) {
  double s = sin(x), c = cos(x);
  double j0 = s / x;
  double jm = c / x;
  if (l == 0) { jl = j0; jm1 = jm; return; }
  double j1 = (s / x - c) / x;
  for (int ll = 2; ll <= l; ++ll) {
    double t = (2.0 * ll - 1.0) / x * j1 - j0;
    j0 = j1; j1 = t;
  }
  jl = j1; jm1 = j0;
}

__global__ void setup_kernel(float* tab) {
  int id = threadIdx.x;
  if (id < NS * NK) {            // wave 0: zeros + norms
    int l = id / NK, j = id % NK;
    double nu = l + 0.5;
    double mu = 4.0 * nu * nu;
    double b  = ((double)(j + 1) + 0.5 * nu - 0.25) * M_PI;
    double b8 = 8.0 * b;
    double x = b - (mu - 1.0) / b8
                 - 4.0 * (mu - 1.0) * (7.0 * mu - 31.0) / (3.0 * b8 * b8 * b8)
                 - 32.0 * (mu - 1.0) * (83.0 * mu * mu - 982.0 * mu + 3779.0) /
                   (15.0 * b8 * b8 * b8 * b8 * b8);
    double jl, jm1;
    for (int it = 0; it < 4; ++it) {
      jl_pair(x, l, jl, jm1);
      double dj = jm1 - (l + 1.0) / x * jl;   // j_l'(x)
      x -= jl / dj;
    }
    tab[id] = (float)x;
    jl_pair(x, l, jl, jm1);
    double jp1 = (2.0 * l + 1.0) / x * jl - jm1;   // j_{l+1}(x)
    tab[NS * NK + id] = (float)(sqrt(2.0) / fabs(jp1));
  }
  if (id >= 64 && id < 64 + NC) {  // wave 1: sph-harm prefactors
    int c = id - 64;
    double v;
    if (c == 0) {
      v = 0.5 / sqrt(M_PI);
    } else {
      int l = 1;
      while ((l + 1) * (l + 1) <= c) ++l;
      int m  = c - l * l - l;
      int am = m < 0 ? -m : m;
      double fr = 1.0;
      for (int i2 = l - am + 1; i2 <= l + am; ++i2) fr *= (double)i2;
      double pref = sqrt((2.0 * l + 1.0) / (4.0 * M_PI * fr));
      v = (m != 0) ? sqrt(2.0) * pref : pref;
    }
    tab[2 * NS * NK + c] = (float)v;
  }
}

// ---------------- main kernel ----------------------------------------------
__global__ __launch_bounds__(BT, 4) void torsion_kernel(
    const float* __restrict__ dist, const float* __restrict__ angle,
    const float* __restrict__ phi, const int* __restrict__ idx_kj,
    const float* __restrict__ tab, float* __restrict__ out, int T) {
  __shared__ float s_cbf[GT][NC];                       // 64 x 49
  __shared__ __align__(16) float s_rbf[GT][NR];         // 64 x 42
  __shared__ float s_d[GT];
  __shared__ float s_tab[133];
  __shared__ unsigned short s_map[NF2 + 1];

  const int tid = threadIdx.x;
  const int t0  = blockIdx.x * GT;
  const int nt  = min(GT, T - t0);

  // ---- phase 0: early input loads + LDS tables ----
  float a = 0.0f, ph = 0.0f;
  if (tid < GT) {
    int t = t0 + tid;
    float dd = 1.0f;
    if (t < T) {
      dd = dist[idx_kj[t]] * 0.2f;   // /CUTOFF
      a  = angle[t];
      ph = phi[t];
    }
    s_d[tid] = dd;
  }
  if (tid < 133) s_tab[tid] = tab[tid];
  if (tid < NF2) {
    int ii = tid / 21, rem2 = tid - 21 * ii, jj = rem2 / 3;
    s_map[tid] = (unsigned short)((ii * NS + jj) | (rem2 << 8));
  }
  __syncthreads();

  if (tid < GT) {
    // ---- cbf: lanes 0..63, per-m streaming Legendre ----
    if (t0 + tid < T) {
      float z = cosf(a), s = sinf(a);
      float sp, cp;
      sincosf(ph, &sp, &cp);
      float cmv[NS], smv[NS];
      cmv[0] = 1.0f; smv[0] = 0.0f;
      cmv[1] = cp;   smv[1] = sp;
#pragma unroll
      for (int m = 2; m < NS; ++m) {
        cmv[m] = 2.0f * cp * cmv[m - 1] - cmv[m - 2];
        smv[m] = 2.0f * cp * smv[m - 1] - smv[m - 2];
      }
      const float* coef = s_tab + 2 * NR;
      float* crow = s_cbf[tid];
      float pmm = 1.0f;
#pragma unroll
      for (int m = 0; m < NS; ++m) {
        float pl1 = pmm, pl2 = 0.0f;
#pragma unroll
        for (int l = m; l < NS; ++l) {
          float plm;
          if (l == m)          plm = pmm;
          else if (l == m + 1) plm = (float)(2 * m + 1) * z * pmm;
          else                 plm = ((float)(2 * l - 1) * z * pl1 -
                                      (float)(l + m - 1) * pl2) *
                                     (float)(1.0 / (double)(l - m));
          int cpn = l * l + l + m;
          if (m == 0) {
            crow[cpn] = coef[cpn] * plm;
          } else {
            crow[cpn] = coef[cpn] * cmv[m] * plm;
            crow[l * l + l - m] = coef[l * l + l - m] * smv[m] * plm;
          }
          pl2 = pl1; pl1 = plm;
        }
        pmm = (float)(-1 - 2 * m) * s * pmm;   // P[m+1][m+1]
      }
    }
  } else {
    // ---- rbf: threads 64..255 cover 64*42 = 2688 = 14*192 items ----
    int j  = tid - 64;
    int t  = j / NR;               // j<192 -> t in 0..4
    int cc = j - NR * t;
    int i2 = j;
    float* rlin = &s_rbf[0][0];
#pragma unroll 2
    for (int it = 0; it < 14; ++it) {
      int l = (cc * 43) >> 8;      // cc/6 for cc<42
      float x = s_d[t] * s_tab[cc];
      float sx, cx;
      sincosf(x, &sx, &cx);
      float invx = 1.0f / x;
      float jm = sx * invx;
      float jc;
      if (l == 0) jc = jm;
      else {
        jc = (sx * invx - cx) * invx;
#pragma unroll
        for (int ll = 2; ll <= 6; ++ll) {
          if (ll <= l) {
            float tt = (float)(2 * ll - 1) * invx * jc - jm;
            jm = jc; jc = tt;
          }
        }
      }
      rlin[i2] = s_tab[NR + cc] * jc;
      i2 += 192;
      cc += 24; t += 4;            // 192 = 4*42 + 24
      if (cc >= NR) { cc -= NR; ++t; }
    }
  }
  __syncthreads();

  // ---- store: 16B/lane, pair-row decomposition (588 floats = 147 f32x4) ----
  const f32x2* r2 = (const f32x2*)&s_rbf[0][0];   // row stride 21 f32x2

  auto body = [&](int i, int p, int k, f32x4* o4) {
    int t2 = p << 1;
    int c2 = k << 1;
    int toff0 = (c2 >= NF2) ? 1 : 0;
    int cc0 = c2 - (toff0 ? NF2 : 0);
    int ta = t2 + toff0;
    unsigned mp0 = s_map[cc0];
    float cv0 = s_cbf[ta][mp0 & 0xff];
    f32x2 rv0 = r2[ta * 21 + (mp0 >> 8)];
    int c21 = c2 + 1;
    int toff1 = (c21 >= NF2) ? 1 : 0;
    int cc1 = c21 - (toff1 ? NF2 : 0);
    int tb = t2 + toff1;
    unsigned mp1 = s_map[cc1];
    float cv1 = s_cbf[tb][mp1 & 0xff];
    f32x2 rv1 = r2[tb * 21 + (mp1 >> 8)];
    f32x4 ov = {cv0 * rv0.x, cv0 * rv0.y, cv1 * rv1.x, cv1 * rv1.y};
    __builtin_nontemporal_store(ov, o4 + i);
  };

  if (nt == GT) {
    f32x4* o4 = (f32x4*)out + (size_t)blockIdx.x * 4704;  // 64*294/4
    int i = tid, p = 0, k = tid;
    if (k >= NF2) { k -= NF2; p = 1; }
#pragma unroll 3
    for (int it = 0; it < 18; ++it) {      // 18*256 + 96 = 4704
      body(i, p, k, o4);
      i += BT; k += 109; ++p;              // 256 = 147 + 109
      if (k >= NF2) { k -= NF2; ++p; }
    }
    if (tid < 96) body(i, p, k, o4);
  } else {
    // tail block: float2 path, any nt
    f32x2* o2 = (f32x2*)out + (size_t)t0 * NF2;
    int tot = nt * NF2;
    for (int i = tid; i < tot; i += BT) {
      int t  = i / NF2;
      int c2 = i - NF2 * t;
      unsigned mp = s_map[c2];
      float cv = s_cbf[t][mp & 0xff];
      f32x2 rv = r2[t * 21 + (mp >> 8)];
      f32x2 ov = cv * rv;
      __builtin_nontemporal_store(ov, o2 + i);
    }
  }
}

// ---------------- launch ----------------------------------------------------
extern "C" void kernel_launch(void* const* d_in, const int* in_sizes, int n_in,
                              void* d_out, int out_size, void* d_ws, size_t ws_size,
                              hipStream_t stream) {
  const float* dist  = (const float*)d_in[0];
  const float* angle = (const float*)d_in[1];
  const float* phi   = (const float*)d_in[2];
  const int*   idx   = (const int*)d_in[3];
  float* out = (float*)d_out;
  float* tab = (float*)d_ws;          // 133 floats
  int T = in_sizes[1];

  hipLaunchKernelGGL(setup_kernel, dim3(1), dim3(128), 0, stream, tab);
  int nb = (T + GT - 1) / GT;
  hipLaunchKernelGGL(torsion_kernel, dim3(nb), dim3(BT), 0, stream,
                     dist, angle, phi, idx, tab, out, T);
}